// Round 4
// baseline (266.669 us; speedup 1.0000x reference)
//
#include <hip/hip_runtime.h>

#define N_NODES 50000
#define N_EDGES 800000
#define CH 128
#define TR 32    // rows per GEMM block
#define NB 196   // scan blocks: 196*256 = 50176 >= N_NODES

// ---- degree count: 4 edges per thread (int4), int atomics ----
__global__ __launch_bounds__(256) void k_deg(const int* __restrict__ rowv,
                                             int* __restrict__ deg) {
    int e4 = blockIdx.x * 256 + threadIdx.x;
    if (e4 < N_EDGES / 4) {
        int4 r = ((const int4*)rowv)[e4];
        atomicAdd(&deg[r.x], 1);
        atomicAdd(&deg[r.y], 1);
        atomicAdd(&deg[r.z], 1);
        atomicAdd(&deg[r.w], 1);
    }
}

// ---- scan phase A: per-block sum of deg ----
__global__ __launch_bounds__(256) void k_bsum(const int* __restrict__ deg,
                                              int* __restrict__ bsum) {
    int i = blockIdx.x * 256 + threadIdx.x;
    int d = (i < N_NODES) ? deg[i] : 0;
    #pragma unroll
    for (int o = 32; o > 0; o >>= 1) d += __shfl_down(d, o, 64);
    __shared__ int ws[4];
    int lane = threadIdx.x & 63, wv = threadIdx.x >> 6;
    if (lane == 0) ws[wv] = d;
    __syncthreads();
    if (threadIdx.x == 0) bsum[blockIdx.x] = ws[0] + ws[1] + ws[2] + ws[3];
}

// ---- scan phase B: single block exclusive-scans the NB block sums ----
__global__ __launch_bounds__(256) void k_bscan(const int* __restrict__ bsum,
                                               int* __restrict__ boff) {
    int t = threadIdx.x;
    int v = (t < NB) ? bsum[t] : 0;
    int lane = t & 63, wv = t >> 6;
    int inc = v;
    #pragma unroll
    for (int d = 1; d < 64; d <<= 1) {
        int u = __shfl_up(inc, d, 64);
        if (lane >= d) inc += u;
    }
    __shared__ int ws[4];
    if (lane == 63) ws[wv] = inc;
    __syncthreads();
    int off = 0;
    for (int w = 0; w < wv; ++w) off += ws[w];
    if (t < NB) boff[t] = off + inc - v;   // exclusive prefix
}

// ---- scan phase C: intra-block scan + block offset -> row_ptr/cursor/dinv ----
__global__ __launch_bounds__(256) void k_rowptr(const int* __restrict__ deg,
                                                const int* __restrict__ boff,
                                                int* __restrict__ row_ptr,
                                                int* __restrict__ cursor,
                                                float* __restrict__ dinv) {
    int i = blockIdx.x * 256 + threadIdx.x;
    int d = (i < N_NODES) ? deg[i] : 0;
    int lane = threadIdx.x & 63, wv = threadIdx.x >> 6;
    int inc = d;
    #pragma unroll
    for (int s = 1; s < 64; s <<= 1) {
        int u = __shfl_up(inc, s, 64);
        if (lane >= s) inc += u;
    }
    __shared__ int ws[4];
    if (lane == 63) ws[wv] = inc;
    __syncthreads();
    int off = boff[blockIdx.x];
    for (int w = 0; w < wv; ++w) off += ws[w];
    int pos = off + inc - d;               // exclusive prefix for node i
    if (i < N_NODES) {
        row_ptr[i] = pos;
        cursor[i]  = pos;
        dinv[i] = rsqrtf((float)(d > 0 ? d : 1));
    }
    if (blockIdx.x == 0 && threadIdx.x == 0) row_ptr[N_NODES] = N_EDGES;
}

// ---- xs = dinv[row] * x[row][:]  (dense, coalesced) ----
__global__ __launch_bounds__(256) void k_scale(const float* __restrict__ x,
                                               const float* __restrict__ dinv,
                                               float* __restrict__ xs) {
    int i4 = blockIdx.x * 256 + threadIdx.x;          // float4 index
    if (i4 < N_NODES * (CH / 4)) {
        int row = i4 >> 5;                            // 32 float4 per row
        float w = dinv[row];
        float4 v = ((const float4*)x)[i4];
        ((float4*)xs)[i4] = make_float4(v.x * w, v.y * w, v.z * w, v.w * w);
    }
}

// ---- counting-sort edges into CSR ----
__global__ __launch_bounds__(256) void k_fill(const int* __restrict__ rowv,
                                              const int* __restrict__ colv,
                                              int* __restrict__ cursor,
                                              int* __restrict__ csr_col) {
    int e = blockIdx.x * 256 + threadIdx.x;
    if (e < N_EDGES) {
        int pos = atomicAdd(&cursor[rowv[e]], 1);
        csr_col[pos] = colv[e];
    }
}

// ---- per-node gather-reduce over PRE-SCALED xs: pure adds, no dinv gather ----
__global__ __launch_bounds__(256) void k_agg_s(const int* __restrict__ row_ptr,
                                               const int* __restrict__ csr_col,
                                               const float* __restrict__ dinv,
                                               const float* __restrict__ xs,
                                               float* __restrict__ agg) {
    int gid = blockIdx.x * 256 + threadIdx.x;
    int n = gid >> 6;
    int lane = threadIdx.x & 63;
    if (n >= N_NODES) return;
    int j = row_ptr[n], end = row_ptr[n + 1];
    const float2* __restrict__ x2 = (const float2*)xs;
    float ax = 0.f, ay = 0.f;
    for (; j + 4 <= end; j += 4) {       // 4 independent gathers in flight
        int c0 = csr_col[j], c1 = csr_col[j + 1], c2 = csr_col[j + 2], c3 = csr_col[j + 3];
        float2 v0 = x2[c0 * 64 + lane];
        float2 v1 = x2[c1 * 64 + lane];
        float2 v2 = x2[c2 * 64 + lane];
        float2 v3 = x2[c3 * 64 + lane];
        ax += v0.x + v1.x + v2.x + v3.x;
        ay += v0.y + v1.y + v2.y + v3.y;
    }
    for (; j < end; ++j) {
        int c = csr_col[j];
        float2 v = x2[c * 64 + lane];
        ax += v.x; ay += v.y;
    }
    float dr = dinv[n];
    ((float2*)agg)[n * 64 + lane] = make_float2(ax * dr, ay * dr);
}

// ---- fallback (ws too small for xs): gather dinv per edge ----
__global__ __launch_bounds__(256) void k_agg(const int* __restrict__ row_ptr,
                                             const int* __restrict__ csr_col,
                                             const float* __restrict__ dinv,
                                             const float* __restrict__ x,
                                             float* __restrict__ agg) {
    int gid = blockIdx.x * 256 + threadIdx.x;
    int n = gid >> 6;
    int lane = threadIdx.x & 63;
    if (n >= N_NODES) return;
    int j = row_ptr[n], end = row_ptr[n + 1];
    const float2* __restrict__ x2 = (const float2*)x;
    float ax = 0.f, ay = 0.f;
    for (; j + 4 <= end; j += 4) {
        int c0 = csr_col[j], c1 = csr_col[j + 1], c2 = csr_col[j + 2], c3 = csr_col[j + 3];
        float w0 = dinv[c0], w1 = dinv[c1], w2 = dinv[c2], w3 = dinv[c3];
        float2 v0 = x2[c0 * 64 + lane];
        float2 v1 = x2[c1 * 64 + lane];
        float2 v2 = x2[c2 * 64 + lane];
        float2 v3 = x2[c3 * 64 + lane];
        ax = fmaf(v0.x, w0, ax); ay = fmaf(v0.y, w0, ay);
        ax = fmaf(v1.x, w1, ax); ay = fmaf(v1.y, w1, ay);
        ax = fmaf(v2.x, w2, ax); ay = fmaf(v2.y, w2, ay);
        ax = fmaf(v3.x, w3, ax); ay = fmaf(v3.y, w3, ay);
    }
    for (; j < end; ++j) {
        int c = csr_col[j];
        float w = dinv[c];
        float2 v = x2[c * 64 + lane];
        ax = fmaf(v.x, w, ax); ay = fmaf(v.y, w, ay);
    }
    float dr = dinv[n];
    ((float2*)agg)[n * 64 + lane] = make_float2(ax * dr, ay * dr);
}

// ---- in-place GEMM: io (N x 128, holds agg) -> io = io @ W (128 x 128) ----
__global__ __launch_bounds__(256) void k_gemm(float* __restrict__ io,
                                              const float* __restrict__ W) {
    __shared__ float sW[CH * CH];   // 64 KB
    __shared__ float sA[TR * CH];   // 16 KB
    int t = threadIdx.x;

    const float4* W4 = (const float4*)W;
    float4* sW4 = (float4*)sW;
    #pragma unroll 4
    for (int i = t; i < CH * CH / 4; i += 256) sW4[i] = W4[i];

    int row0 = blockIdx.x * TR;
    int rows = N_NODES - row0; if (rows > TR) rows = TR;
    float4* sA4 = (float4*)sA;
    const float4* A4 = (const float4*)(io + (size_t)row0 * CH);
    for (int i = t; i < TR * CH / 4; i += 256) {
        int r = i >> 5;  // 32 float4 per row
        sA4[i] = (r < rows) ? A4[i] : make_float4(0.f, 0.f, 0.f, 0.f);
    }
    __syncthreads();

    int r0 = (t >> 5) * 4;
    int c0 = (t & 31) * 4;
    float acc[4][4] = {};
    for (int k = 0; k < CH; ++k) {
        float4 b = *(const float4*)&sW[k * CH + c0];
        #pragma unroll
        for (int i = 0; i < 4; ++i) {
            float a = sA[(r0 + i) * CH + k];
            acc[i][0] = fmaf(a, b.x, acc[i][0]);
            acc[i][1] = fmaf(a, b.y, acc[i][1]);
            acc[i][2] = fmaf(a, b.z, acc[i][2]);
            acc[i][3] = fmaf(a, b.w, acc[i][3]);
        }
    }
    #pragma unroll
    for (int i = 0; i < 4; ++i) {
        if (r0 + i < rows) {
            *(float4*)(io + (size_t)(row0 + r0 + i) * CH + c0) =
                make_float4(acc[i][0], acc[i][1], acc[i][2], acc[i][3]);
        }
    }
}

extern "C" void kernel_launch(void* const* d_in, const int* in_sizes, int n_in,
                              void* d_out, int out_size, void* d_ws, size_t ws_size,
                              hipStream_t stream) {
    const float* x = (const float*)d_in[0];
    const float* W = (const float*)d_in[1];
    const int* edge = (const int*)d_in[2];
    const int* rowv = edge;            // edge_index[0][:]
    const int* colv = edge + N_EDGES;  // edge_index[1][:]
    float* out = (float*)d_out;

    // ws layout (ints unless noted):
    //   deg | row_ptr[N+1] | cursor | dinv(f32) | bsum | boff | pad | csr_col | xs(f32, optional)
    int*   deg     = (int*)d_ws;
    int*   row_ptr = deg + N_NODES;
    int*   cursor  = row_ptr + N_NODES + 1;
    float* dinv    = (float*)(cursor + N_NODES);
    int*   bsum    = (int*)(dinv + N_NODES);
    int*   boff    = bsum + NB;
    int*   csr_col = boff + NB + 7;    // keep 16B-ish alignment headroom
    float* xs      = (float*)(csr_col + N_EDGES);

    size_t need_scaled = ((char*)(xs + (size_t)N_NODES * CH)) - (char*)d_ws;
    bool use_scaled = ws_size >= need_scaled;

    hipMemsetAsync(deg, 0, (size_t)N_NODES * sizeof(int), stream);

    k_deg   <<<(N_EDGES / 4 + 255) / 256, 256, 0, stream>>>(rowv, deg);
    k_bsum  <<<NB, 256, 0, stream>>>(deg, bsum);
    k_bscan <<<1, 256, 0, stream>>>(bsum, boff);
    k_rowptr<<<NB, 256, 0, stream>>>(deg, boff, row_ptr, cursor, dinv);
    if (use_scaled) {
        k_scale<<<(N_NODES * (CH / 4) + 255) / 256, 256, 0, stream>>>(x, dinv, xs);
    }
    k_fill  <<<(N_EDGES + 255) / 256, 256, 0, stream>>>(rowv, colv, cursor, csr_col);
    if (use_scaled) {
        k_agg_s<<<(N_NODES * 64 + 255) / 256, 256, 0, stream>>>(row_ptr, csr_col, dinv, xs, out);
    } else {
        k_agg  <<<(N_NODES * 64 + 255) / 256, 256, 0, stream>>>(row_ptr, csr_col, dinv, x, out);
    }
    k_gemm  <<<(N_NODES + TR - 1) / TR, 256, 0, stream>>>(out, W);
}

// Round 5
// 244.864 us; speedup vs baseline: 1.0890x; 1.0890x over previous
//
#include <hip/hip_runtime.h>

#define N_NODES 50000
#define N_EDGES 800000
#define CH 128
#define NB 196   // scan blocks: 196*256 = 50176 >= N_NODES

typedef __attribute__((ext_vector_type(8))) short bf16x8;
typedef __attribute__((ext_vector_type(4))) float f32x4;

static __device__ inline short f2bf(float f) {
    union { float f; unsigned u; } v; v.f = f;
    unsigned r = v.u + 0x7fff + ((v.u >> 16) & 1);   // RNE
    return (short)(r >> 16);
}

// ---- degree count: 4 edges per thread (int4), int atomics ----
__global__ __launch_bounds__(256) void k_deg(const int* __restrict__ rowv,
                                             int* __restrict__ deg) {
    int e4 = blockIdx.x * 256 + threadIdx.x;
    if (e4 < N_EDGES / 4) {
        int4 r = ((const int4*)rowv)[e4];
        atomicAdd(&deg[r.x], 1);
        atomicAdd(&deg[r.y], 1);
        atomicAdd(&deg[r.z], 1);
        atomicAdd(&deg[r.w], 1);
    }
}

// ---- scan phase A: per-block sum of deg ----
__global__ __launch_bounds__(256) void k_bsum(const int* __restrict__ deg,
                                              int* __restrict__ bsum) {
    int i = blockIdx.x * 256 + threadIdx.x;
    int d = (i < N_NODES) ? deg[i] : 0;
    #pragma unroll
    for (int o = 32; o > 0; o >>= 1) d += __shfl_down(d, o, 64);
    __shared__ int ws[4];
    int lane = threadIdx.x & 63, wv = threadIdx.x >> 6;
    if (lane == 0) ws[wv] = d;
    __syncthreads();
    if (threadIdx.x == 0) bsum[blockIdx.x] = ws[0] + ws[1] + ws[2] + ws[3];
}

// ---- scan phase B: single block exclusive-scans the NB block sums ----
__global__ __launch_bounds__(256) void k_bscan(const int* __restrict__ bsum,
                                               int* __restrict__ boff) {
    int t = threadIdx.x;
    int v = (t < NB) ? bsum[t] : 0;
    int lane = t & 63, wv = t >> 6;
    int inc = v;
    #pragma unroll
    for (int d = 1; d < 64; d <<= 1) {
        int u = __shfl_up(inc, d, 64);
        if (lane >= d) inc += u;
    }
    __shared__ int ws[4];
    if (lane == 63) ws[wv] = inc;
    __syncthreads();
    int off = 0;
    for (int w = 0; w < wv; ++w) off += ws[w];
    if (t < NB) boff[t] = off + inc - v;   // exclusive prefix
}

// ---- scan phase C: intra-block scan + block offset -> row_ptr/cursor/dinv ----
__global__ __launch_bounds__(256) void k_rowptr(const int* __restrict__ deg,
                                                const int* __restrict__ boff,
                                                int* __restrict__ row_ptr,
                                                int* __restrict__ cursor,
                                                float* __restrict__ dinv) {
    int i = blockIdx.x * 256 + threadIdx.x;
    int d = (i < N_NODES) ? deg[i] : 0;
    int lane = threadIdx.x & 63, wv = threadIdx.x >> 6;
    int inc = d;
    #pragma unroll
    for (int s = 1; s < 64; s <<= 1) {
        int u = __shfl_up(inc, s, 64);
        if (lane >= s) inc += u;
    }
    __shared__ int ws[4];
    if (lane == 63) ws[wv] = inc;
    __syncthreads();
    int off = boff[blockIdx.x];
    for (int w = 0; w < wv; ++w) off += ws[w];
    int pos = off + inc - d;               // exclusive prefix for node i
    if (i < N_NODES) {
        row_ptr[i] = pos;
        cursor[i]  = pos;
        dinv[i] = rsqrtf((float)(d > 0 ? d : 1));
    }
    if (blockIdx.x == 0 && threadIdx.x == 0) row_ptr[N_NODES] = N_EDGES;
}

// ---- counting-sort edges into CSR (4 edges/thread, int4 loads) ----
__global__ __launch_bounds__(256) void k_fill(const int* __restrict__ rowv,
                                              const int* __restrict__ colv,
                                              int* __restrict__ cursor,
                                              int* __restrict__ csr_col) {
    int e4 = blockIdx.x * 256 + threadIdx.x;
    if (e4 < N_EDGES / 4) {
        int4 r = ((const int4*)rowv)[e4];
        int4 c = ((const int4*)colv)[e4];
        csr_col[atomicAdd(&cursor[r.x], 1)] = c.x;
        csr_col[atomicAdd(&cursor[r.y], 1)] = c.y;
        csr_col[atomicAdd(&cursor[r.z], 1)] = c.z;
        csr_col[atomicAdd(&cursor[r.w], 1)] = c.w;
    }
}

// ---- per-node gather-reduce: one wave per node, 2 channels/lane (round-3 form) ----
__global__ __launch_bounds__(256) void k_agg(const int* __restrict__ row_ptr,
                                             const int* __restrict__ csr_col,
                                             const float* __restrict__ dinv,
                                             const float* __restrict__ x,
                                             float* __restrict__ agg) {
    int gid = blockIdx.x * 256 + threadIdx.x;
    int n = gid >> 6;
    int lane = threadIdx.x & 63;
    if (n >= N_NODES) return;
    int j = row_ptr[n], end = row_ptr[n + 1];
    const float2* __restrict__ x2 = (const float2*)x;
    float ax = 0.f, ay = 0.f;
    for (; j + 4 <= end; j += 4) {       // 4 independent gathers in flight
        int c0 = csr_col[j], c1 = csr_col[j + 1], c2 = csr_col[j + 2], c3 = csr_col[j + 3];
        float w0 = dinv[c0], w1 = dinv[c1], w2 = dinv[c2], w3 = dinv[c3];
        float2 v0 = x2[c0 * 64 + lane];
        float2 v1 = x2[c1 * 64 + lane];
        float2 v2 = x2[c2 * 64 + lane];
        float2 v3 = x2[c3 * 64 + lane];
        ax = fmaf(v0.x, w0, ax); ay = fmaf(v0.y, w0, ay);
        ax = fmaf(v1.x, w1, ax); ay = fmaf(v1.y, w1, ay);
        ax = fmaf(v2.x, w2, ax); ay = fmaf(v2.y, w2, ay);
        ax = fmaf(v3.x, w3, ax); ay = fmaf(v3.y, w3, ay);
    }
    for (; j < end; ++j) {
        int c = csr_col[j];
        float w = dinv[c];
        float2 v = x2[c * 64 + lane];
        ax = fmaf(v.x, w, ax); ay = fmaf(v.y, w, ay);
    }
    float dr = dinv[n];
    ((float2*)agg)[n * 64 + lane] = make_float2(ax * dr, ay * dr);
}

// ---- bf16 MFMA GEMM, in-place: io (N x 128 f32) -> io = io @ W ----
// 64 rows/block, 4 waves; wave w: rows 16w..16w+15, all 128 cols.
// LDS: sA [64][136] bf16, sWT [128][136] bf16 (W transposed, [n][k]).
#define LDP 136   // padded row length (bf16): +8 pad -> 16B-aligned rows, 2-way banks only
__global__ __launch_bounds__(256) void k_gemm(float* __restrict__ io,
                                              const float* __restrict__ W) {
    __shared__ short sA[64 * LDP];
    __shared__ short sWT[CH * LDP];
    int t = threadIdx.x;
    int row0 = blockIdx.x * 64;

    // stage W^T as bf16: thread reads W[k][n] coalesced, writes sWT[n][k]
    for (int i = t; i < CH * CH; i += 256) {
        int k = i >> 7, n = i & 127;
        sWT[n * LDP + k] = f2bf(W[i]);
    }
    // stage A tile as bf16 (float4 global reads)
    const float4* A4 = (const float4*)(io + (size_t)row0 * CH);
    for (int i4 = t; i4 < 64 * (CH / 4); i4 += 256) {
        int r = i4 >> 5, c4 = (i4 & 31) * 4;
        float4 v = (row0 + r < N_NODES) ? A4[i4] : make_float4(0.f, 0.f, 0.f, 0.f);
        short* d = &sA[r * LDP + c4];
        d[0] = f2bf(v.x); d[1] = f2bf(v.y); d[2] = f2bf(v.z); d[3] = f2bf(v.w);
    }
    __syncthreads();

    int lane = t & 63, w = t >> 6;
    int m = lane & 15, q = lane >> 4;

    // A fragments for this wave's 16 rows: a[kk], k = kk*32 + q*8 + j
    bf16x8 afr[4];
    #pragma unroll
    for (int kk = 0; kk < 4; ++kk)
        afr[kk] = *(const bf16x8*)&sA[(16 * w + m) * LDP + kk * 32 + q * 8];

    f32x4 acc[8];
    #pragma unroll
    for (int c = 0; c < 8; ++c) acc[c] = (f32x4){0.f, 0.f, 0.f, 0.f};

    #pragma unroll
    for (int c = 0; c < 8; ++c) {
        #pragma unroll
        for (int kk = 0; kk < 4; ++kk) {
            bf16x8 bfr = *(const bf16x8*)&sWT[(c * 16 + m) * LDP + kk * 32 + q * 8];
            acc[c] = __builtin_amdgcn_mfma_f32_16x16x32_bf16(afr[kk], bfr, acc[c], 0, 0, 0);
        }
    }

    // D: row = q*4 + reg (within wave's 16 rows), col = c*16 + m
    #pragma unroll
    for (int c = 0; c < 8; ++c) {
        #pragma unroll
        for (int r = 0; r < 4; ++r) {
            int row = row0 + 16 * w + q * 4 + r;
            if (row < N_NODES) io[(size_t)row * CH + c * 16 + m] = acc[c][r];
        }
    }
}

extern "C" void kernel_launch(void* const* d_in, const int* in_sizes, int n_in,
                              void* d_out, int out_size, void* d_ws, size_t ws_size,
                              hipStream_t stream) {
    const float* x = (const float*)d_in[0];
    const float* W = (const float*)d_in[1];
    const int* edge = (const int*)d_in[2];
    const int* rowv = edge;            // edge_index[0][:]
    const int* colv = edge + N_EDGES;  // edge_index[1][:]
    float* out = (float*)d_out;

    // ws layout: deg | row_ptr[N+1] | cursor | dinv(f32) | bsum | boff | pad | csr_col
    int*   deg     = (int*)d_ws;
    int*   row_ptr = deg + N_NODES;
    int*   cursor  = row_ptr + N_NODES + 1;
    float* dinv    = (float*)(cursor + N_NODES);
    int*   bsum    = (int*)(dinv + N_NODES);
    int*   boff    = bsum + NB;
    int*   csr_col = boff + NB + 7;

    hipMemsetAsync(deg, 0, (size_t)N_NODES * sizeof(int), stream);

    k_deg   <<<(N_EDGES / 4 + 255) / 256, 256, 0, stream>>>(rowv, deg);
    k_bsum  <<<NB, 256, 0, stream>>>(deg, bsum);
    k_bscan <<<1, 256, 0, stream>>>(bsum, boff);
    k_rowptr<<<NB, 256, 0, stream>>>(deg, boff, row_ptr, cursor, dinv);
    k_fill  <<<(N_EDGES / 4 + 255) / 256, 256, 0, stream>>>(rowv, colv, cursor, csr_col);
    k_agg   <<<(N_NODES * 64 + 255) / 256, 256, 0, stream>>>(row_ptr, csr_col, dinv, x, out);
    k_gemm  <<<(N_NODES + 63) / 64, 256, 0, stream>>>(out, W);
}

// Round 6
// 215.728 us; speedup vs baseline: 1.2361x; 1.1351x over previous
//
#include <hip/hip_runtime.h>

#define N_NODES 50000
#define N_EDGES 800000
#define CH 128
#define NB 196   // scan blocks: 196*256 = 50176 >= N_NODES

typedef __attribute__((ext_vector_type(8))) short bf16x8;
typedef __attribute__((ext_vector_type(4))) float f32x4;

static __device__ inline unsigned short f2bf(float f) {
    union { float f; unsigned u; } v; v.f = f;
    unsigned r = v.u + 0x7fff + ((v.u >> 16) & 1);   // RNE
    return (unsigned short)(r >> 16);
}
static __device__ inline float bflo(unsigned v) { union { unsigned u; float f; } c; c.u = v << 16; return c.f; }
static __device__ inline float bfhi(unsigned v) { union { unsigned u; float f; } c; c.u = v & 0xffff0000u; return c.f; }

// ---- degree count: 4 edges per thread (int4), int atomics ----
__global__ __launch_bounds__(256) void k_deg(const int* __restrict__ rowv,
                                             int* __restrict__ deg) {
    int e4 = blockIdx.x * 256 + threadIdx.x;
    if (e4 < N_EDGES / 4) {
        int4 r = ((const int4*)rowv)[e4];
        atomicAdd(&deg[r.x], 1);
        atomicAdd(&deg[r.y], 1);
        atomicAdd(&deg[r.z], 1);
        atomicAdd(&deg[r.w], 1);
    }
}

// ---- xh = bf16(x), dense coalesced ----
__global__ __launch_bounds__(256) void k_half(const float* __restrict__ x,
                                              unsigned short* __restrict__ xh) {
    int i4 = blockIdx.x * 256 + threadIdx.x;   // float4 index
    if (i4 < N_NODES * (CH / 4)) {
        float4 v = ((const float4*)x)[i4];
        uint2 p;
        p.x = (unsigned)f2bf(v.x) | ((unsigned)f2bf(v.y) << 16);
        p.y = (unsigned)f2bf(v.z) | ((unsigned)f2bf(v.w) << 16);
        ((uint2*)xh)[i4] = p;
    }
}

// ---- scan phase A: per-block sum of deg ----
__global__ __launch_bounds__(256) void k_bsum(const int* __restrict__ deg,
                                              int* __restrict__ bsum) {
    int i = blockIdx.x * 256 + threadIdx.x;
    int d = (i < N_NODES) ? deg[i] : 0;
    #pragma unroll
    for (int o = 32; o > 0; o >>= 1) d += __shfl_down(d, o, 64);
    __shared__ int ws[4];
    int lane = threadIdx.x & 63, wv = threadIdx.x >> 6;
    if (lane == 0) ws[wv] = d;
    __syncthreads();
    if (threadIdx.x == 0) bsum[blockIdx.x] = ws[0] + ws[1] + ws[2] + ws[3];
}

// ---- scan phase B: single block exclusive-scans the NB block sums ----
__global__ __launch_bounds__(256) void k_bscan(const int* __restrict__ bsum,
                                               int* __restrict__ boff) {
    int t = threadIdx.x;
    int v = (t < NB) ? bsum[t] : 0;
    int lane = t & 63, wv = t >> 6;
    int inc = v;
    #pragma unroll
    for (int d = 1; d < 64; d <<= 1) {
        int u = __shfl_up(inc, d, 64);
        if (lane >= d) inc += u;
    }
    __shared__ int ws[4];
    if (lane == 63) ws[wv] = inc;
    __syncthreads();
    int off = 0;
    for (int w = 0; w < wv; ++w) off += ws[w];
    if (t < NB) boff[t] = off + inc - v;   // exclusive prefix
}

// ---- scan phase C: intra-block scan + block offset -> row_ptr/cursor/dinv ----
__global__ __launch_bounds__(256) void k_rowptr(const int* __restrict__ deg,
                                                const int* __restrict__ boff,
                                                int* __restrict__ row_ptr,
                                                int* __restrict__ cursor,
                                                float* __restrict__ dinv) {
    int i = blockIdx.x * 256 + threadIdx.x;
    int d = (i < N_NODES) ? deg[i] : 0;
    int lane = threadIdx.x & 63, wv = threadIdx.x >> 6;
    int inc = d;
    #pragma unroll
    for (int s = 1; s < 64; s <<= 1) {
        int u = __shfl_up(inc, s, 64);
        if (lane >= s) inc += u;
    }
    __shared__ int ws[4];
    if (lane == 63) ws[wv] = inc;
    __syncthreads();
    int off = boff[blockIdx.x];
    for (int w = 0; w < wv; ++w) off += ws[w];
    int pos = off + inc - d;               // exclusive prefix for node i
    if (i < N_NODES) {
        row_ptr[i] = pos;
        cursor[i]  = pos;
        dinv[i] = rsqrtf((float)(d > 0 ? d : 1));
    }
    if (blockIdx.x == 0 && threadIdx.x == 0) row_ptr[N_NODES] = N_EDGES;
}

// ---- counting-sort edges into CSR: 1 edge/thread (max latency hiding), u16 cols ----
__global__ __launch_bounds__(256) void k_fill(const int* __restrict__ rowv,
                                              const int* __restrict__ colv,
                                              int* __restrict__ cursor,
                                              unsigned short* __restrict__ csr_col) {
    int e = blockIdx.x * 256 + threadIdx.x;
    if (e < N_EDGES) {
        int pos = atomicAdd(&cursor[rowv[e]], 1);
        csr_col[pos] = (unsigned short)colv[e];
    }
}

// ---- per-node gather-reduce over bf16 xh: one wave/node, 2 ch/lane (one uint) ----
__global__ __launch_bounds__(256) void k_agg_h(const int* __restrict__ row_ptr,
                                               const unsigned short* __restrict__ csr_col,
                                               const float* __restrict__ dinv,
                                               const unsigned short* __restrict__ xh,
                                               unsigned short* __restrict__ aggh) {
    int gid = blockIdx.x * 256 + threadIdx.x;
    int n = gid >> 6;
    int lane = threadIdx.x & 63;
    if (n >= N_NODES) return;
    int j = row_ptr[n], end = row_ptr[n + 1];
    const unsigned* __restrict__ x2 = (const unsigned*)xh;   // 2 bf16 per uint
    float ax = 0.f, ay = 0.f;
    for (; j + 4 <= end; j += 4) {       // 4 independent gathers in flight
        int c0 = csr_col[j], c1 = csr_col[j + 1], c2 = csr_col[j + 2], c3 = csr_col[j + 3];
        float w0 = dinv[c0], w1 = dinv[c1], w2 = dinv[c2], w3 = dinv[c3];
        unsigned v0 = x2[c0 * 64 + lane];
        unsigned v1 = x2[c1 * 64 + lane];
        unsigned v2 = x2[c2 * 64 + lane];
        unsigned v3 = x2[c3 * 64 + lane];
        ax = fmaf(bflo(v0), w0, ax); ay = fmaf(bfhi(v0), w0, ay);
        ax = fmaf(bflo(v1), w1, ax); ay = fmaf(bfhi(v1), w1, ay);
        ax = fmaf(bflo(v2), w2, ax); ay = fmaf(bfhi(v2), w2, ay);
        ax = fmaf(bflo(v3), w3, ax); ay = fmaf(bfhi(v3), w3, ay);
    }
    for (; j < end; ++j) {
        int c = csr_col[j];
        float w = dinv[c];
        unsigned v = x2[c * 64 + lane];
        ax = fmaf(bflo(v), w, ax); ay = fmaf(bfhi(v), w, ay);
    }
    float dr = dinv[n];
    unsigned out = (unsigned)f2bf(ax * dr) | ((unsigned)f2bf(ay * dr) << 16);
    ((unsigned*)aggh)[n * 64 + lane] = out;
}

// ---- bf16 MFMA GEMM: out = aggh(bf16) @ W ; A frags direct from global (L2-hot) ----
// 64 rows/block, 4 waves; wave w: rows 16w..16w+15, all 128 cols.
#define LDP 136   // padded row length for sWT (bf16)
__global__ __launch_bounds__(256) void k_gemm(const unsigned short* __restrict__ aggh,
                                              const float* __restrict__ W,
                                              float* __restrict__ out) {
    __shared__ short sWT[CH * LDP];   // 34 KB: W^T in bf16, [n][k]
    int t = threadIdx.x;
    int row0 = blockIdx.x * 64;

    // stage W^T as bf16: thread reads W[k][n] coalesced, writes sWT[n][k]
    for (int i = t; i < CH * CH; i += 256) {
        int k = i >> 7, n = i & 127;
        sWT[n * LDP + k] = (short)f2bf(W[i]);
    }
    __syncthreads();

    int lane = t & 63, w = t >> 6;
    int m = lane & 15, q = lane >> 4;

    int row = row0 + 16 * w + m;
    int rc = row < N_NODES ? row : N_NODES - 1;      // clamp (guarded at store)
    const short* arow = (const short*)aggh + (size_t)rc * CH;
    bf16x8 afr[4];
    #pragma unroll
    for (int kk = 0; kk < 4; ++kk)
        afr[kk] = *(const bf16x8*)(arow + kk * 32 + q * 8);

    f32x4 acc[8];
    #pragma unroll
    for (int c = 0; c < 8; ++c) acc[c] = (f32x4){0.f, 0.f, 0.f, 0.f};

    #pragma unroll
    for (int c = 0; c < 8; ++c) {
        #pragma unroll
        for (int kk = 0; kk < 4; ++kk) {
            bf16x8 bfr = *(const bf16x8*)&sWT[(c * 16 + m) * LDP + kk * 32 + q * 8];
            acc[c] = __builtin_amdgcn_mfma_f32_16x16x32_bf16(afr[kk], bfr, acc[c], 0, 0, 0);
        }
    }

    // D: row = q*4 + reg (within wave's 16 rows), col = c*16 + m
    #pragma unroll
    for (int c = 0; c < 8; ++c) {
        #pragma unroll
        for (int r = 0; r < 4; ++r) {
            int orow = row0 + 16 * w + q * 4 + r;
            if (orow < N_NODES) out[(size_t)orow * CH + c * 16 + m] = acc[c][r];
        }
    }
}

extern "C" void kernel_launch(void* const* d_in, const int* in_sizes, int n_in,
                              void* d_out, int out_size, void* d_ws, size_t ws_size,
                              hipStream_t stream) {
    const float* x = (const float*)d_in[0];
    const float* W = (const float*)d_in[1];
    const int* edge = (const int*)d_in[2];
    const int* rowv = edge;            // edge_index[0][:]
    const int* colv = edge + N_EDGES;  // edge_index[1][:]
    float* out = (float*)d_out;

    // ws layout: deg | row_ptr[N+1] | cursor | dinv | bsum | boff | csr_col(u16) | xh | aggh
    char* p = (char*)d_ws;
    int*   deg     = (int*)p;            p += (size_t)N_NODES * 4;
    int*   row_ptr = (int*)p;            p += (size_t)(N_NODES + 1) * 4;
    int*   cursor  = (int*)p;            p += (size_t)N_NODES * 4;
    float* dinv    = (float*)p;          p += (size_t)N_NODES * 4;
    int*   bsum    = (int*)p;            p += NB * 4;
    int*   boff    = (int*)p;            p += NB * 4;
    p = (char*)(((uintptr_t)p + 255) & ~(uintptr_t)255);
    unsigned short* csr_col = (unsigned short*)p;  p += (size_t)N_EDGES * 2;
    p = (char*)(((uintptr_t)p + 255) & ~(uintptr_t)255);
    unsigned short* xh   = (unsigned short*)p;     p += (size_t)N_NODES * CH * 2;
    unsigned short* aggh = (unsigned short*)p;     // + N_NODES*CH*2  (total ~28.0 MB)

    hipMemsetAsync(deg, 0, (size_t)N_NODES * sizeof(int), stream);

    k_deg   <<<(N_EDGES / 4 + 255) / 256, 256, 0, stream>>>(rowv, deg);
    k_half  <<<(N_NODES * (CH / 4) + 255) / 256, 256, 0, stream>>>(x, xh);
    k_bsum  <<<NB, 256, 0, stream>>>(deg, bsum);
    k_bscan <<<1, 256, 0, stream>>>(bsum, boff);
    k_rowptr<<<NB, 256, 0, stream>>>(deg, boff, row_ptr, cursor, dinv);
    k_fill  <<<(N_EDGES + 255) / 256, 256, 0, stream>>>(rowv, colv, cursor, csr_col);
    k_agg_h <<<(N_NODES * 64 + 255) / 256, 256, 0, stream>>>(row_ptr, csr_col, dinv, xh, aggh);
    k_gemm  <<<(N_NODES + 63) / 64, 256, 0, stream>>>(aggh, W, out);
}